// Round 1
// baseline (4939.756 us; speedup 1.0000x reference)
//
#include <hip/hip_runtime.h>
#include <cmath>

#define BB 64
#define TT 250
#define CC 1024
#define UU 512
#define GG 1536   // 3U

// workspace layout (float offsets)
#define O_XGF 0
#define O_XGB 24576000      // T*B*G = 250*64*1536
#define O_UT  49152000      // 2*512*3*512 = 1,572,864
#define O_HT  50724864      // 2 bufs * 2 dirs * 512*64 = 131,072
#define O_MF  50855936      // T*B = 16,000
// total = 50,871,936 floats = ~194 MB

__global__ __launch_bounds__(256) void prep_kernel(
    const unsigned char* __restrict__ mraw,
    const float* __restrict__ Uf, const float* __restrict__ Ub,
    float* __restrict__ ut, float* __restrict__ mf, float* __restrict__ ht)
{
  int idx = blockIdx.x * 256 + threadIdx.x;
  // transpose U into ut[(d*512+u)*3 + g][k] = U_d[k][g*512+u]
  if (idx < 2*512*3*512) {
    int k = idx & 511;
    int r = idx >> 9;
    int g = r % 3;
    int rest = r / 3;        // d*512 + u
    int u = rest & 511;
    int dd = rest >> 9;
    const float* Um = dd ? Ub : Uf;
    ut[idx] = Um[k*GG + (g << 9) + u];
  }
  // zero both h ping-pong buffers
  if (idx < 131072) ht[idx] = 0.0f;
  // mask -> float, transposed to [t][b]; detect bool8 vs int32/float32 storage.
  // mask[0][1] is guaranteed true (seq_len >= 125): bool8 => byte1 == 1;
  // int32/float32 little-endian => byte1 == 0.
  if (idx < BB*TT) {
    int b = idx / TT, t = idx - b*TT;
    bool bytefmt = (mraw[1] == 1);
    bool mv = bytefmt ? (mraw[idx] != 0) : (((const int*)mraw)[idx] != 0);
    mf[t*BB + b] = mv ? 1.0f : 0.0f;
  }
}

// C = A(16000x1024) * W(1024x1536) + bias, for both directions (N split by block),
// output written as XG[t][b][g] (scan-friendly layout).
__global__ __launch_bounds__(256) void gemm_xg(
    const float* __restrict__ A,
    const float* __restrict__ Wf, const float* __restrict__ Wb,
    const float* __restrict__ bf, const float* __restrict__ bb,
    float* __restrict__ xgf, float* __restrict__ xgb)
{
  __shared__ float As[16][132];   // transposed A tile, padded (132*4B = 33*16B: keeps 16B align + bank spread)
  __shared__ float Bs[16][128];
  const int tid = threadIdx.x;
  const int m0 = blockIdx.x * 128;          // 125 tiles
  const int n0 = blockIdx.y * 128;          // 24 tiles over 3072
  const int d  = (n0 >= GG) ? 1 : 0;
  const int nl0 = n0 - d*GG;
  const float* Wm  = d ? Wb : Wf;
  const float* bias = d ? bb : bf;          // row 0 of b
  float* xg = d ? xgb : xgf;
  const int tm = (tid >> 4) << 3;
  const int tn = (tid & 15) << 3;
  float acc[8][8];
  #pragma unroll
  for (int i = 0; i < 8; i++) {
    #pragma unroll
    for (int j = 0; j < 8; j++) acc[i][j] = 0.0f;
  }
  for (int k0 = 0; k0 < CC; k0 += 16) {
    #pragma unroll
    for (int j = 0; j < 2; j++) {
      int f = tid*2 + j;                 // 0..511
      int r = f >> 2;                    // 0..127
      int kk = (f & 3) << 2;             // 0,4,8,12
      float4 av = *(const float4*)(A + (size_t)(m0+r)*CC + k0 + kk);
      As[kk+0][r] = av.x; As[kk+1][r] = av.y; As[kk+2][r] = av.z; As[kk+3][r] = av.w;
    }
    #pragma unroll
    for (int j = 0; j < 2; j++) {
      int f = tid*2 + j;
      int kr = f >> 5;                   // 0..15
      int nn = (f & 31) << 2;            // 0..124
      *(float4*)&Bs[kr][nn] = *(const float4*)(Wm + (size_t)(k0+kr)*GG + nl0 + nn);
    }
    __syncthreads();
    #pragma unroll
    for (int k = 0; k < 16; k++) {
      float4 a0 = *(const float4*)&As[k][tm];
      float4 a1 = *(const float4*)&As[k][tm+4];
      float4 b0 = *(const float4*)&Bs[k][tn];
      float4 b1 = *(const float4*)&Bs[k][tn+4];
      float av[8] = {a0.x,a0.y,a0.z,a0.w,a1.x,a1.y,a1.z,a1.w};
      float bv[8] = {b0.x,b0.y,b0.z,b0.w,b1.x,b1.y,b1.z,b1.w};
      #pragma unroll
      for (int i = 0; i < 8; i++) {
        #pragma unroll
        for (int jj = 0; jj < 8; jj++) acc[i][jj] = fmaf(av[i], bv[jj], acc[i][jj]);
      }
    }
    __syncthreads();
  }
  float bv8[8];
  #pragma unroll
  for (int j = 0; j < 8; j++) bv8[j] = bias[nl0 + tn + j];
  #pragma unroll
  for (int i = 0; i < 8; i++) {
    int m = m0 + tm + i;
    int b = m / TT;
    int t = m - b*TT;
    float* o = xg + (size_t)(t*BB + b)*GG + nl0 + tn;
    float4 o0 = {acc[i][0]+bv8[0], acc[i][1]+bv8[1], acc[i][2]+bv8[2], acc[i][3]+bv8[3]};
    float4 o1 = {acc[i][4]+bv8[4], acc[i][5]+bv8[5], acc[i][6]+bv8[6], acc[i][7]+bv8[7]};
    *(float4*)o = o0; *(float4*)(o+4) = o1;
  }
}

// One GRU time-step, both directions. grid = 256 blocks (d = bid>>7, utile = bid&127),
// block = 256 threads = 4 waves; wave handles one u (lane = batch row b).
__global__ __launch_bounds__(256) void gru_step(
    const float* __restrict__ xgf, const float* __restrict__ xgb,
    const float* __restrict__ ut, const float* __restrict__ bf,
    const float* __restrict__ bb, const float* __restrict__ mf,
    float* __restrict__ ht, float* __restrict__ out, int step)
{
  __shared__ float hs[2][8192];   // 64 KB: double-buffered 128-k chunks of ht[k][b]
  const int tid  = threadIdx.x;
  const int lane = tid & 63;                 // batch index b
  const int d    = blockIdx.x >> 7;
  int u_ = ((blockIdx.x & 127) << 2) | (tid >> 6);
  const int u = __builtin_amdgcn_readfirstlane(u_);   // wave-uniform -> SGPR addressing
  const int t = d ? (TT-1-step) : step;
  const int cur = step & 1;
  const float* hin  = ht + (((cur << 1) | d) << 15);        // [512][64]
  float*       hout = ht + ((((cur ^ 1) << 1) | d) << 15);
  const float* xg = (d ? xgb : xgf) + (size_t)(t*BB + lane)*GG;
  float xz = xg[u];
  float xr = xg[512 + u];
  float xh = xg[1024 + u];
  float hprev = hin[(u << 6) | lane];
  float m = mf[t*BB + lane];
  const float* bias = (d ? bb : bf) + GG;    // recurrent bias row b[1]
  float b1z = bias[u], b1r = bias[512 + u], b1h = bias[1024 + u];
  const float* uz = ut + ((((d << 9) | u) * 3) << 9);
  const float* ur = uz + 512;
  const float* uh = ur + 512;

  // stage chunk 0
  {
    const float4* s = (const float4*)hin;
    float4* dst = (float4*)hs[0];
    #pragma unroll
    for (int j = 0; j < 8; j++) dst[j*256 + tid] = s[j*256 + tid];
  }
  __syncthreads();

  float az = 0.0f, ar = 0.0f, ah = 0.0f;
  for (int c = 0; c < 4; c++) {
    float4 stg[8];
    if (c < 3) {                      // issue next-chunk loads early (hide under compute)
      const float4* s = (const float4*)(hin + (c+1)*8192);
      #pragma unroll
      for (int j = 0; j < 8; j++) stg[j] = s[j*256 + tid];
    }
    const float* hb  = hs[c & 1];
    const float* uzc = uz + (c << 7);
    const float* urc = ur + (c << 7);
    const float* uhc = uh + (c << 7);
    #pragma unroll 32
    for (int k = 0; k < 128; k++) {
      float hk = hb[(k << 6) | lane];      // stride-1 across lanes: conflict-free
      az = fmaf(hk, uzc[k], az);           // uzc[k]: wave-uniform -> scalar load
      ar = fmaf(hk, urc[k], ar);
      ah = fmaf(hk, uhc[k], ah);
    }
    if (c < 3) {                      // write staged chunk after compute
      float4* dst = (float4*)hs[(c+1) & 1];
      #pragma unroll
      for (int j = 0; j < 8; j++) dst[j*256 + tid] = stg[j];
    }
    __syncthreads();
  }

  float hz = az + b1z, hr = ar + b1r, hh = ah + b1h;
  float z  = 1.0f / (1.0f + expf(-(xz + hz)));
  float r  = 1.0f / (1.0f + expf(-(xr + hr)));
  float ccv = tanhf(xh + r*hh);
  float hn = z*hprev + (1.0f - z)*ccv;
  hn = (m != 0.0f) ? hn : hprev;           // masked step carries h
  hout[(u << 6) | lane] = hn;
  out[(size_t)(lane*TT + t)*1024 + (d << 9) + u] = hn;     // seq_out[b][t][d*512+u]
  if (step == TT-1)
    out[(size_t)16384000 + (lane << 10) + (d << 9) + u] = hn;  // state_out[b][d*512+u]
}

extern "C" void kernel_launch(void* const* d_in, const int* in_sizes, int n_in,
                              void* d_out, int out_size, void* d_ws, size_t ws_size,
                              hipStream_t stream) {
  const float* X  = (const float*)d_in[0];
  const unsigned char* Mk = (const unsigned char*)d_in[1];
  const float* Wf = (const float*)d_in[2];
  const float* Uf = (const float*)d_in[3];
  const float* bf = (const float*)d_in[4];
  const float* Wb = (const float*)d_in[5];
  const float* Ub = (const float*)d_in[6];
  const float* bb = (const float*)d_in[7];
  float* out = (float*)d_out;
  float* ws  = (float*)d_ws;
  float* xgf = ws + O_XGF;
  float* xgb = ws + O_XGB;
  float* ut  = ws + O_UT;
  float* ht  = ws + O_HT;
  float* mf  = ws + O_MF;

  prep_kernel<<<dim3(6144), dim3(256), 0, stream>>>(Mk, Uf, Ub, ut, mf, ht);
  gemm_xg<<<dim3(125, 24), dim3(256), 0, stream>>>(X, Wf, Wb, bf, bb, xgf, xgb);
  for (int s = 0; s < TT; s++)
    gru_step<<<dim3(256), dim3(256), 0, stream>>>(xgf, xgb, ut, bf, bb, mf, ht, out, s);
}